// Round 2
// baseline (434.774 us; speedup 1.0000x reference)
//
#include <hip/hip_runtime.h>
#include <stdint.h>

// QNetSNN: B=16384 rows, HIDDEN=64, T=40. Wave=row, lane=neuron.
// Spike vectors -> 64-bit ballot masks (wave-uniform SGPRs); matvecs become
// sparse selection-sums. ALL arithmetic in fp64 to track the harness's
// float64 reference (fp32 spike-flip noise ~0.1 > threshold 0.0734).
// Weights stay fp32 (f32->f64 conversion exact):
//   LDS 64 KB: Wsrec_t | Warec_t | Wcin1_t | Wcin2_t, each [k][n] 64x64 fp32.
//   Global d_ws (L1-resident, 30 KB): Wsin_t [48][64], Wain_t [8][64], Wcrec_t [64][64].

__device__ __forceinline__ uint64_t rfl64(uint64_t x) {
    uint32_t lo = (uint32_t)__builtin_amdgcn_readfirstlane((int)(uint32_t)(x & 0xFFFFFFFFull));
    uint32_t hi = (uint32_t)__builtin_amdgcn_readfirstlane((int)(uint32_t)(x >> 32));
    return ((uint64_t)hi << 32) | (uint64_t)lo;
}

__global__ void snn_prep(const float* __restrict__ Wsin, const float* __restrict__ Wain,
                         const float* __restrict__ Wcrec, float* __restrict__ ws) {
    int tid = blockIdx.x * 256 + threadIdx.x;
    // W_s_in: (64,48) row-major -> ws[k*64+n]
    if (tid < 3072) { int n = tid / 48; int k = tid - n * 48; ws[k * 64 + n] = Wsin[tid]; }
    // W_a_in: (64,8) -> ws[3072 + k*64+n]
    if (tid < 512)  { int n = tid / 8;  int k = tid - n * 8;  ws[3072 + k * 64 + n] = Wain[tid]; }
    // W_c_rec: (64,64) -> ws[3584 + k*64+n]
    if (tid < 4096) { int n = tid >> 6; int k = tid & 63;     ws[3584 + k * 64 + n] = Wcrec[tid]; }
}

__launch_bounds__(1024, 4)
__global__ void snn_main(const float* __restrict__ state, const float* __restrict__ action,
                         const float* __restrict__ Wsrec, const float* __restrict__ Wcin,
                         const float* __restrict__ Warec, const float* __restrict__ Wro,
                         const float* __restrict__ ws, float* __restrict__ out) {
    __shared__ float lds[16384];  // 64 KB -> 2 blocks/CU

    const int tid = threadIdx.x;
    for (int e = tid; e < 16384; e += 1024) {
        int mat = e >> 12;
        int sub = e & 4095;
        int n = sub >> 6;
        int k = sub & 63;
        float val;
        if (mat == 0)      val = Wsrec[n * 64 + k];
        else if (mat == 1) val = Warec[n * 64 + k];
        else if (mat == 2) val = Wcin[n * 128 + k];          // W_c_in[:, :64]
        else               val = Wcin[n * 128 + 64 + k];     // W_c_in[:, 64:]
        lds[(e & 0x3000) + k * 64 + n] = val;  // transposed [k][n]
    }
    __syncthreads();

    const int lane = tid & 63;
    const int wave = tid >> 6;
    const int row  = blockIdx.x * 16 + wave;

    // Encoder current (constant over time), fp64. 50*(f32) is exact in double.
    double cur = 0.0;
    if (lane < 24)      cur = fmax( 50.0 * (double)state[row * 24 + lane], 0.0);
    else if (lane < 48) cur = fmax(-50.0 * (double)state[row * 24 + lane - 24], 0.0);
    else if (lane < 52) cur = fmax( 50.0 * (double)action[row * 4 + lane - 48], 0.0);
    else if (lane < 56) cur = fmax(-50.0 * (double)action[row * 4 + lane - 52], 0.0);

    const double wro = (double)Wro[lane];
    const float* __restrict__ wsin_g  = ws;
    const float* __restrict__ wain_g  = ws + 3072;
    const float* __restrict__ wcrec_g = ws + 3584;

    double venc = 0.0, v = 0.0, icur = 0.0, vli = 0.0, ili = 0.0, vmax = 0.0;
    uint64_t zmask = 0;  // z_c of previous step

    for (int t = 0; t < 40; ++t) {
        // ---- encoder LIF: v += 0.1*(0 - v + cur); z=(v-1>0); v -= z*v ----
        venc = venc + 0.1 * (cur - venc);
        bool esp = (venc - 1.0) > 0.0;
        venc = esp ? 0.0 : venc;
        uint64_t em = rfl64(__ballot(esp));

        // ---- layer s: lif_step(xs_s, z_prev, v, i, W_s_in, W_s_rec) ----
        double acc = icur - 0.2 * icur;                  // i_dec
        uint64_t m = em & 0x0000FFFFFFFFFFFFull;
        while (m) { int k = __builtin_ctzll(m); m &= m - 1; acc += (double)wsin_g[(k << 6) + lane]; }
        m = zmask;
        while (m) { int k = __builtin_ctzll(m); m &= m - 1; acc += (double)lds[(k << 6) + lane]; }
        double vd = v + 0.1 * (icur - v);                // uses old i
        bool z = (vd - 1.0) > 0.0;
        v = z ? 0.0 : vd;
        icur = acc;
        uint64_t zsm = rfl64(__ballot(z));

        // ---- layer a: lif_step(xs_a, z_s, v, i, W_a_in, W_a_rec) ----
        acc = icur - 0.2 * icur;
        m = (em >> 48);
        while (m) { int k = __builtin_ctzll(m); m &= m - 1; acc += (double)wain_g[(k << 6) + lane]; }
        m = zsm;
        while (m) { int k = __builtin_ctzll(m); m &= m - 1; acc += (double)lds[4096 + (k << 6) + lane]; }
        vd = v + 0.1 * (icur - v);
        z = (vd - 1.0) > 0.0;
        v = z ? 0.0 : vd;
        icur = acc;
        uint64_t zam = rfl64(__ballot(z));

        // ---- layer c: lif_step([z_s,z_a], z_a, v, i, W_c_in, W_c_rec) ----
        acc = icur - 0.2 * icur;
        m = zsm;
        while (m) { int k = __builtin_ctzll(m); m &= m - 1; acc += (double)lds[8192 + (k << 6) + lane]; }
        m = zam;
        while (m) {
            int k = __builtin_ctzll(m); m &= m - 1;
            acc += (double)lds[12288 + (k << 6) + lane];   // W_c_in[:, 64:]
            acc += (double)wcrec_g[(k << 6) + lane];       // W_c_rec
        }
        vd = v + 0.1 * (icur - v);
        z = (vd - 1.0) > 0.0;                            // z_c
        v = z ? 0.0 : vd;
        icur = acc;

        // ---- readout li_step(z_c, vli, ili, W_ro) ----
        double p = z ? wro : 0.0;
        #pragma unroll
        for (int off = 32; off >= 1; off >>= 1) p += __shfl_xor(p, off, 64);
        double vnew = vli + 0.1 * (ili - vli);           // uses old ili
        ili = (ili - 0.2 * ili) + p;
        vli = vnew;
        vmax = fmax(vmax, vli);                          // voltages[0]=0, max>=0

        zmask = rfl64(__ballot(z));
    }

    if (lane == 0) out[row] = (float)vmax;
}

extern "C" void kernel_launch(void* const* d_in, const int* in_sizes, int n_in,
                              void* d_out, int out_size, void* d_ws, size_t ws_size,
                              hipStream_t stream) {
    const float* state  = (const float*)d_in[0];
    const float* action = (const float*)d_in[1];
    const float* Wsin   = (const float*)d_in[2];
    const float* Wsrec  = (const float*)d_in[3];
    const float* Wain   = (const float*)d_in[4];
    const float* Warec  = (const float*)d_in[5];
    const float* Wcin   = (const float*)d_in[6];
    const float* Wcrec  = (const float*)d_in[7];
    const float* Wro    = (const float*)d_in[8];
    float* out = (float*)d_out;
    float* ws  = (float*)d_ws;

    const int B = in_sizes[0] / 24;          // 16384
    snn_prep<<<16, 256, 0, stream>>>(Wsin, Wain, Wcrec, ws);
    snn_main<<<B / 16, 1024, 0, stream>>>(state, action, Wsrec, Wcin, Warec, Wro, ws, out);
}

// Round 3
// 260.644 us; speedup vs baseline: 1.6681x; 1.6681x over previous
//
#include <hip/hip_runtime.h>
#include <stdint.h>

// QNetSNN: B=16384, HIDDEN=64, T=40. Wave=row, lane=neuron.
// R3: all-f64 weights (no in-loop cvt), f64 fold of Wcin2+Wcrec, merged zsm
// pair loop (Warec||Wcin1 via dwordx4), encoder always-on precompute, unroll-2
// dual accumulators. Fallback to proven R2 path if ws_size too small.
//
// LDS 64 KB: wsrec64 [k][n] (32 KB) | fold64 = Wcin[:,64:]+Wcrec [k][n] (32 KB)
// ws  (f64): wsin64_t [48][64] | wain64_t [8][64] | wpair (Warec,Wcin1) [64][64][2]

__device__ __forceinline__ uint64_t rfl64(uint64_t x) {
    uint32_t lo = (uint32_t)__builtin_amdgcn_readfirstlane((int)(uint32_t)(x & 0xFFFFFFFFull));
    uint32_t hi = (uint32_t)__builtin_amdgcn_readfirstlane((int)(uint32_t)(x >> 32));
    return ((uint64_t)hi << 32) | (uint64_t)lo;
}

// ---------------- R3 fast path ----------------

__global__ void snn_prep64(const float* __restrict__ Wsin, const float* __restrict__ Wain,
                           const float* __restrict__ Warec, const float* __restrict__ Wcin,
                           double* __restrict__ ws) {
    int tid = blockIdx.x * 256 + threadIdx.x;   // 0..11775
    if (tid < 3072) {
        int k = tid >> 6, n = tid & 63;
        ws[tid] = (double)Wsin[n * 48 + k];
    } else if (tid < 3584) {
        int r = tid - 3072; int k = r >> 6, n = r & 63;
        ws[tid] = (double)Wain[n * 8 + k];
    } else if (tid < 11776) {
        int r = tid - 3584; int k = r >> 7; int rem = r & 127; int n = rem >> 1;
        ws[tid] = (rem & 1) ? (double)Wcin[n * 128 + k]    // Wcin1 (cols :64)
                            : (double)Warec[n * 64 + k];
    }
}

__launch_bounds__(1024, 4)
__global__ void snn_main64(const float* __restrict__ state, const float* __restrict__ action,
                           const float* __restrict__ Wsrec, const float* __restrict__ Wcin,
                           const float* __restrict__ Wcrec, const float* __restrict__ Wro,
                           const double* __restrict__ ws, float* __restrict__ out) {
    __shared__ double lds[8192];  // 64 KB: [0,4096) wsrec64 [k][n]; [4096,8192) fold64 [k][n]

    const int tid = threadIdx.x;
    for (int e = tid; e < 8192; e += 1024) {
        int half = e >> 12; int sub = e & 4095; int k = sub >> 6; int n = sub & 63;
        double val;
        if (half == 0) val = (double)Wsrec[n * 64 + k];
        else           val = (double)Wcin[n * 128 + 64 + k] + (double)Wcrec[n * 64 + k];
        lds[e] = val;   // e == (half<<12)+(k<<6)+n : lane-consecutive writes, conflict-free
    }
    __syncthreads();

    const int lane = tid & 63;
    const int wave = tid >> 6;
    const int row  = blockIdx.x * 16 + wave;

    double cur = 0.0;
    if (lane < 24)      cur = fmax( 50.0 * (double)state[row * 24 + lane], 0.0);
    else if (lane < 48) cur = fmax(-50.0 * (double)state[row * 24 + lane - 24], 0.0);
    else if (lane < 52) cur = fmax( 50.0 * (double)action[row * 4 + lane - 48], 0.0);
    else if (lane < 56) cur = fmax(-50.0 * (double)action[row * 4 + lane - 52], 0.0);

    // Always-on encoder lanes: from reset, venc = 0 + 0.1*(cur-0) bit-identically
    // every step, so (v1-1)>0 <=> spikes at EVERY t (incl. t=0). Exact predicate.
    double v1 = 0.0 + 0.1 * (cur - 0.0);
    bool alw = (v1 - 1.0) > 0.0;
    double curv = alw ? 0.0 : cur;               // variable lanes simulate; always lanes inert
    uint64_t AM = rfl64(__ballot(alw));

    const double* __restrict__ wsin64 = ws;
    const double* __restrict__ wain64 = ws + 3072;
    const double* __restrict__ wpair  = ws + 3584;
    const double wro = (double)Wro[lane];

    // Precompute per-lane always-on input sums (amortized over 40 steps).
    double Ssin = 0.0, Sain = 0.0;
    {
        uint64_t m = AM & 0x0000FFFFFFFFFFFFull;
        while (m) { int k = __builtin_ctzll(m); m &= m - 1; Ssin += wsin64[(k << 6) + lane]; }
        m = AM >> 48;
        while (m) { int k = __builtin_ctzll(m); m &= m - 1; Sain += wain64[(k << 6) + lane]; }
    }

    double venc = 0.0, v = 0.0, icur = 0.0, vli = 0.0, ili = 0.0, vmax = 0.0;
    uint64_t zmask = 0;  // z_c of previous step

    for (int t = 0; t < 40; ++t) {
        // ---- encoder (variable lanes only; always lanes contribute via Ssin/Sain) ----
        venc = venc + 0.1 * (curv - venc);
        bool esp = (venc - 1.0) > 0.0;
        venc = esp ? 0.0 : venc;
        uint64_t em = rfl64(__ballot(esp));

        // ---- layer s ----
        double acc = (icur - 0.2 * icur) + Ssin;
        {
            double a0 = 0.0, a1 = 0.0;
            uint64_t m = em & 0x0000FFFFFFFFFFFFull;        // variable state bits (~few)
            while (m) {
                int k = __builtin_ctzll(m); m &= m - 1; a0 += wsin64[(k << 6) + lane];
                if (m) { k = __builtin_ctzll(m); m &= m - 1; a1 += wsin64[(k << 6) + lane]; }
            }
            m = zmask;                                       // recurrent, f64 LDS
            while (m) {
                int k = __builtin_ctzll(m); m &= m - 1; a0 += lds[(k << 6) + lane];
                if (m) { k = __builtin_ctzll(m); m &= m - 1; a1 += lds[(k << 6) + lane]; }
            }
            acc += a0 + a1;
        }
        double vd = v + 0.1 * (icur - v);
        bool z = (vd - 1.0) > 0.0;
        v = z ? 0.0 : vd;
        icur = acc;
        uint64_t zsm = rfl64(__ballot(z));

        // ---- merged zsm loop: Warec (layer a) + Wcin1 (layer c) in one dwordx4 ----
        double pA0 = 0.0, pA1 = 0.0, pC0 = 0.0, pC1 = 0.0;
        {
            uint64_t m = zsm;
            while (m) {
                int k = __builtin_ctzll(m); m &= m - 1;
                const double* p = wpair + (k << 7) + (lane << 1);
                pA0 += p[0]; pC0 += p[1];
                if (m) {
                    k = __builtin_ctzll(m); m &= m - 1;
                    const double* q = wpair + (k << 7) + (lane << 1);
                    pA1 += q[0]; pC1 += q[1];
                }
            }
        }

        // ---- layer a ----
        acc = (icur - 0.2 * icur) + Sain + (pA0 + pA1);
        {
            uint64_t m = (em >> 48);                         // variable action bits (<=4)
            while (m) { int k = __builtin_ctzll(m); m &= m - 1; acc += wain64[(k << 6) + lane]; }
        }
        vd = v + 0.1 * (icur - v);
        z = (vd - 1.0) > 0.0;
        v = z ? 0.0 : vd;
        icur = acc;
        uint64_t zam = rfl64(__ballot(z));

        // ---- layer c ----
        acc = (icur - 0.2 * icur) + (pC0 + pC1);
        {
            double a0 = 0.0, a1 = 0.0;
            uint64_t m = zam;                                // fold64 = Wcin2 + Wcrec, f64 LDS
            while (m) {
                int k = __builtin_ctzll(m); m &= m - 1; a0 += lds[4096 + (k << 6) + lane];
                if (m) { k = __builtin_ctzll(m); m &= m - 1; a1 += lds[4096 + (k << 6) + lane]; }
            }
            acc += a0 + a1;
        }
        vd = v + 0.1 * (icur - v);
        z = (vd - 1.0) > 0.0;                                // z_c
        v = z ? 0.0 : vd;
        icur = acc;

        // ---- LI readout ----
        double p = z ? wro : 0.0;
        #pragma unroll
        for (int off = 32; off >= 1; off >>= 1) p += __shfl_xor(p, off, 64);
        double vnew = vli + 0.1 * (ili - vli);
        ili = (ili - 0.2 * ili) + p;
        vli = vnew;
        vmax = fmax(vmax, vli);

        zmask = rfl64(__ballot(z));
    }

    if (lane == 0) out[row] = (float)vmax;
}

// ---------------- R2 fallback path (proven correct) ----------------

__global__ void snn_prep32(const float* __restrict__ Wsin, const float* __restrict__ Wain,
                           const float* __restrict__ Wcrec, float* __restrict__ ws) {
    int tid = blockIdx.x * 256 + threadIdx.x;
    if (tid < 3072) { int n = tid / 48; int k = tid - n * 48; ws[k * 64 + n] = Wsin[tid]; }
    if (tid < 512)  { int n = tid / 8;  int k = tid - n * 8;  ws[3072 + k * 64 + n] = Wain[tid]; }
    if (tid < 4096) { int n = tid >> 6; int k = tid & 63;     ws[3584 + k * 64 + n] = Wcrec[tid]; }
}

__launch_bounds__(1024, 4)
__global__ void snn_main32(const float* __restrict__ state, const float* __restrict__ action,
                           const float* __restrict__ Wsrec, const float* __restrict__ Wcin,
                           const float* __restrict__ Warec, const float* __restrict__ Wro,
                           const float* __restrict__ ws, float* __restrict__ out) {
    __shared__ float lds[16384];
    const int tid = threadIdx.x;
    for (int e = tid; e < 16384; e += 1024) {
        int mat = e >> 12; int sub = e & 4095; int n = sub >> 6; int k = sub & 63;
        float val;
        if (mat == 0)      val = Wsrec[n * 64 + k];
        else if (mat == 1) val = Warec[n * 64 + k];
        else if (mat == 2) val = Wcin[n * 128 + k];
        else               val = Wcin[n * 128 + 64 + k];
        lds[(e & 0x3000) + k * 64 + n] = val;
    }
    __syncthreads();
    const int lane = tid & 63; const int wave = tid >> 6; const int row = blockIdx.x * 16 + wave;
    double cur = 0.0;
    if (lane < 24)      cur = fmax( 50.0 * (double)state[row * 24 + lane], 0.0);
    else if (lane < 48) cur = fmax(-50.0 * (double)state[row * 24 + lane - 24], 0.0);
    else if (lane < 52) cur = fmax( 50.0 * (double)action[row * 4 + lane - 48], 0.0);
    else if (lane < 56) cur = fmax(-50.0 * (double)action[row * 4 + lane - 52], 0.0);
    const double wro = (double)Wro[lane];
    const float* __restrict__ wsin_g  = ws;
    const float* __restrict__ wain_g  = ws + 3072;
    const float* __restrict__ wcrec_g = ws + 3584;
    double venc = 0.0, v = 0.0, icur = 0.0, vli = 0.0, ili = 0.0, vmax = 0.0;
    uint64_t zmask = 0;
    for (int t = 0; t < 40; ++t) {
        venc = venc + 0.1 * (cur - venc);
        bool esp = (venc - 1.0) > 0.0;
        venc = esp ? 0.0 : venc;
        uint64_t em = rfl64(__ballot(esp));
        double acc = icur - 0.2 * icur;
        uint64_t m = em & 0x0000FFFFFFFFFFFFull;
        while (m) { int k = __builtin_ctzll(m); m &= m - 1; acc += (double)wsin_g[(k << 6) + lane]; }
        m = zmask;
        while (m) { int k = __builtin_ctzll(m); m &= m - 1; acc += (double)lds[(k << 6) + lane]; }
        double vd = v + 0.1 * (icur - v);
        bool z = (vd - 1.0) > 0.0;
        v = z ? 0.0 : vd; icur = acc;
        uint64_t zsm = rfl64(__ballot(z));
        acc = icur - 0.2 * icur;
        m = (em >> 48);
        while (m) { int k = __builtin_ctzll(m); m &= m - 1; acc += (double)wain_g[(k << 6) + lane]; }
        m = zsm;
        while (m) { int k = __builtin_ctzll(m); m &= m - 1; acc += (double)lds[4096 + (k << 6) + lane]; }
        vd = v + 0.1 * (icur - v);
        z = (vd - 1.0) > 0.0;
        v = z ? 0.0 : vd; icur = acc;
        uint64_t zam = rfl64(__ballot(z));
        acc = icur - 0.2 * icur;
        m = zsm;
        while (m) { int k = __builtin_ctzll(m); m &= m - 1; acc += (double)lds[8192 + (k << 6) + lane]; }
        m = zam;
        while (m) {
            int k = __builtin_ctzll(m); m &= m - 1;
            acc += (double)lds[12288 + (k << 6) + lane];
            acc += (double)wcrec_g[(k << 6) + lane];
        }
        vd = v + 0.1 * (icur - v);
        z = (vd - 1.0) > 0.0;
        v = z ? 0.0 : vd; icur = acc;
        double p = z ? wro : 0.0;
        #pragma unroll
        for (int off = 32; off >= 1; off >>= 1) p += __shfl_xor(p, off, 64);
        double vnew = vli + 0.1 * (ili - vli);
        ili = (ili - 0.2 * ili) + p;
        vli = vnew;
        vmax = fmax(vmax, vli);
        zmask = rfl64(__ballot(z));
    }
    if (lane == 0) out[row] = (float)vmax;
}

extern "C" void kernel_launch(void* const* d_in, const int* in_sizes, int n_in,
                              void* d_out, int out_size, void* d_ws, size_t ws_size,
                              hipStream_t stream) {
    const float* state  = (const float*)d_in[0];
    const float* action = (const float*)d_in[1];
    const float* Wsin   = (const float*)d_in[2];
    const float* Wsrec  = (const float*)d_in[3];
    const float* Wain   = (const float*)d_in[4];
    const float* Warec  = (const float*)d_in[5];
    const float* Wcin   = (const float*)d_in[6];
    const float* Wcrec  = (const float*)d_in[7];
    const float* Wro    = (const float*)d_in[8];
    float* out = (float*)d_out;
    const int B = in_sizes[0] / 24;  // 16384

    if (ws_size >= 11776 * sizeof(double)) {
        double* ws = (double*)d_ws;
        snn_prep64<<<46, 256, 0, stream>>>(Wsin, Wain, Warec, Wcin, ws);
        snn_main64<<<B / 16, 1024, 0, stream>>>(state, action, Wsrec, Wcin, Wcrec, Wro, ws, out);
    } else {
        float* ws = (float*)d_ws;
        snn_prep32<<<16, 256, 0, stream>>>(Wsin, Wain, Wcrec, ws);
        snn_main32<<<B / 16, 1024, 0, stream>>>(state, action, Wsrec, Wcin, Warec, Wro, ws, out);
    }
}

// Round 4
// 251.941 us; speedup vs baseline: 1.7257x; 1.0345x over previous
//
#include <hip/hip_runtime.h>
#include <stdint.h>

// QNetSNN: B=16384, HIDDEN=64, T=40. Wave=row, lane=neuron.
// R4: global weights shrunk to f32 (exact on cvt to f64) so the hot pair
// matrix (Warec||Wcin1, float2-interleaved, 32 KB) is L1-resident; step
// reordered so the global pair loop issues before the LDS layer-s loops;
// readout reduction in f32 (feed-forward only, no spike feedback).
//
// LDS 64 KB (f64): wsrec64 [k][n] | fold64 = Wcin[:,64:]+Wcrec [k][n]
// ws   (f32): wsin32_t [48][64] | wain32_t [8][64] | pair float2 [64][64]
//             pair[k*64+n] = { Warec[n][k], Wcin[n][k] }   (47 KB total)

__device__ __forceinline__ uint64_t rfl64(uint64_t x) {
    uint32_t lo = (uint32_t)__builtin_amdgcn_readfirstlane((int)(uint32_t)(x & 0xFFFFFFFFull));
    uint32_t hi = (uint32_t)__builtin_amdgcn_readfirstlane((int)(uint32_t)(x >> 32));
    return ((uint64_t)hi << 32) | (uint64_t)lo;
}

__global__ void snn_prep(const float* __restrict__ Wsin, const float* __restrict__ Wain,
                         const float* __restrict__ Warec, const float* __restrict__ Wcin,
                         float* __restrict__ ws) {
    int tid = blockIdx.x * 256 + threadIdx.x;   // 0..11775
    if (tid < 3072) {
        int k = tid >> 6, n = tid & 63;
        ws[tid] = Wsin[n * 48 + k];
    } else if (tid < 3584) {
        int r = tid - 3072; int k = r >> 6, n = r & 63;
        ws[tid] = Wain[n * 8 + k];
    } else if (tid < 11776) {
        int r = tid - 3584; int k = r >> 7; int rem = r & 127; int n = rem >> 1;
        ws[tid] = (rem & 1) ? Wcin[n * 128 + k]    // .y = Wcin1 (cols :64)
                            : Warec[n * 64 + k];   // .x = Warec
    }
}

__launch_bounds__(1024, 4)
__global__ void snn_main(const float* __restrict__ state, const float* __restrict__ action,
                         const float* __restrict__ Wsrec, const float* __restrict__ Wcin,
                         const float* __restrict__ Wcrec, const float* __restrict__ Wro,
                         const float* __restrict__ ws, float* __restrict__ out) {
    __shared__ double lds[8192];  // [0,4096) wsrec64 [k][n]; [4096,8192) fold64 [k][n]

    const int tid = threadIdx.x;
    for (int e = tid; e < 8192; e += 1024) {
        int half = e >> 12; int sub = e & 4095; int k = sub >> 6; int n = sub & 63;
        double val;
        if (half == 0) val = (double)Wsrec[n * 64 + k];
        else           val = (double)Wcin[n * 128 + 64 + k] + (double)Wcrec[n * 64 + k];
        lds[e] = val;
    }
    __syncthreads();

    const int lane = tid & 63;
    const int wave = tid >> 6;
    const int row  = blockIdx.x * 16 + wave;

    double cur = 0.0;
    if (lane < 24)      cur = fmax( 50.0 * (double)state[row * 24 + lane], 0.0);
    else if (lane < 48) cur = fmax(-50.0 * (double)state[row * 24 + lane - 24], 0.0);
    else if (lane < 52) cur = fmax( 50.0 * (double)action[row * 4 + lane - 48], 0.0);
    else if (lane < 56) cur = fmax(-50.0 * (double)action[row * 4 + lane - 52], 0.0);

    // Always-on lanes: after reset venc = 0 + 0.1*(cur-0) bit-identically every
    // step, so v1>1 <=> spikes every t (incl. t=0). Exact predicate.
    double v1 = 0.0 + 0.1 * (cur - 0.0);
    bool alw = (v1 - 1.0) > 0.0;
    double curv = alw ? 0.0 : cur;
    uint64_t AM = rfl64(__ballot(alw));

    const float*  __restrict__ wsin32 = ws;
    const float*  __restrict__ wain32 = ws + 3072;
    const float2* __restrict__ pair   = (const float2*)(ws + 3584);
    const float wro = Wro[lane];

    // Per-lane always-on input sums (f64 accumulate; f32->f64 cvt exact).
    double Ssin = 0.0, Sain = 0.0;
    {
        uint64_t m = AM & 0x0000FFFFFFFFFFFFull;
        while (m) { int k = __builtin_ctzll(m); m &= m - 1; Ssin += (double)wsin32[(k << 6) + lane]; }
        m = AM >> 48;
        while (m) { int k = __builtin_ctzll(m); m &= m - 1; Sain += (double)wain32[(k << 6) + lane]; }
    }

    double venc = 0.0, v = 0.0, icur = 0.0, vli = 0.0, ili = 0.0, vmax = 0.0;
    uint64_t zmask = 0;  // z_c of previous step

    for (int t = 0; t < 40; ++t) {
        // ---- layer-s threshold: depends only on ENTERING v,icur -> hoist ----
        double vd = v + 0.1 * (icur - v);
        bool zs = (vd - 1.0) > 0.0;
        double vs_new = zs ? 0.0 : vd;
        uint64_t zsm = rfl64(__ballot(zs));

        // ---- pair loop (global float2, L1-resident): Warec + Wcin1 ----
        double pA0 = 0.0, pA1 = 0.0, pC0 = 0.0, pC1 = 0.0;
        {
            uint64_t m = zsm;
            while (m) {
                int k = __builtin_ctzll(m); m &= m - 1;
                float2 w = pair[(k << 6) + lane];
                pA0 += (double)w.x; pC0 += (double)w.y;
                if (m) {
                    k = __builtin_ctzll(m); m &= m - 1;
                    float2 u = pair[(k << 6) + lane];
                    pA1 += (double)u.x; pC1 += (double)u.y;
                }
            }
        }

        // ---- encoder (variable lanes only) ----
        venc = venc + 0.1 * (curv - venc);
        bool esp = (venc - 1.0) > 0.0;
        venc = esp ? 0.0 : venc;
        uint64_t em = rfl64(__ballot(esp));

        // ---- layer-s accumulation ----
        double acc = (icur - 0.2 * icur) + Ssin;
        {
            uint64_t m = em & 0x0000FFFFFFFFFFFFull;   // variable state bits (few)
            while (m) { int k = __builtin_ctzll(m); m &= m - 1; acc += (double)wsin32[(k << 6) + lane]; }
            double a0 = 0.0, a1 = 0.0;
            m = zmask;                                  // recurrent, f64 LDS
            while (m) {
                int k = __builtin_ctzll(m); m &= m - 1; a0 += lds[(k << 6) + lane];
                if (m) { k = __builtin_ctzll(m); m &= m - 1; a1 += lds[(k << 6) + lane]; }
            }
            acc += a0 + a1;
        }
        double icur_s = acc;

        // ---- layer a ----
        vd = vs_new + 0.1 * (icur_s - vs_new);
        bool za = (vd - 1.0) > 0.0;
        double va_new = za ? 0.0 : vd;
        uint64_t zam = rfl64(__ballot(za));

        acc = (icur_s - 0.2 * icur_s) + Sain + (pA0 + pA1);
        {
            uint64_t m = (em >> 48);                    // variable action bits (few)
            while (m) { int k = __builtin_ctzll(m); m &= m - 1; acc += (double)wain32[(k << 6) + lane]; }
        }
        double icur_a = acc;

        // ---- layer c ----
        vd = va_new + 0.1 * (icur_a - va_new);
        bool zc = (vd - 1.0) > 0.0;
        v = zc ? 0.0 : vd;
        zmask = rfl64(__ballot(zc));

        acc = (icur_a - 0.2 * icur_a) + (pC0 + pC1);
        {
            double a0 = 0.0, a1 = 0.0;
            uint64_t m = zam;                           // fold64 = Wcin2 + Wcrec, f64 LDS
            while (m) {
                int k = __builtin_ctzll(m); m &= m - 1; a0 += lds[4096 + (k << 6) + lane];
                if (m) { k = __builtin_ctzll(m); m &= m - 1; a1 += lds[4096 + (k << 6) + lane]; }
            }
            acc += a0 + a1;
        }
        icur = acc;

        // ---- LI readout (feed-forward only -> f32 reduce is safe) ----
        float p = zc ? wro : 0.f;
        #pragma unroll
        for (int off = 32; off >= 1; off >>= 1) p += __shfl_xor(p, off, 64);
        double vnew = vli + 0.1 * (ili - vli);
        ili = (ili - 0.2 * ili) + (double)p;
        vli = vnew;
        vmax = fmax(vmax, vli);
    }

    if (lane == 0) out[row] = (float)vmax;
}

extern "C" void kernel_launch(void* const* d_in, const int* in_sizes, int n_in,
                              void* d_out, int out_size, void* d_ws, size_t ws_size,
                              hipStream_t stream) {
    const float* state  = (const float*)d_in[0];
    const float* action = (const float*)d_in[1];
    const float* Wsin   = (const float*)d_in[2];
    const float* Wsrec  = (const float*)d_in[3];
    const float* Wain   = (const float*)d_in[4];
    const float* Warec  = (const float*)d_in[5];
    const float* Wcin   = (const float*)d_in[6];
    const float* Wcrec  = (const float*)d_in[7];
    const float* Wro    = (const float*)d_in[8];
    float* out = (float*)d_out;
    float* ws  = (float*)d_ws;

    const int B = in_sizes[0] / 24;  // 16384
    snn_prep<<<46, 256, 0, stream>>>(Wsin, Wain, Warec, Wcin, ws);
    snn_main<<<B / 16, 1024, 0, stream>>>(state, action, Wsrec, Wcin, Wcrec, Wro, ws, out);
}